// Round 3
// baseline (4741.814 us; speedup 1.0000x reference)
//
#include <hip/hip_runtime.h>
#include <math.h>

// ASMambaBlock: router + 4-direction Mamba (selective scan) + windowed MHA.
// ALL tensors are float32 (evidence: in/out npz sizes match f32 raw bytes).
// Internal f32 in d_ws. Batch-sliced: per-slice floats = 4096 + R*4376,
// R = BS*1024, BS = largest of {8,4,2,1} fitting ws_size.

#define NSEQ  1024
#define DMODEL 384
#define DINNER 768
#define DSTATE 64
#define XW 152            // dt_rank(24) + 2*d_state(128)

// PERMS closed-form: side=32. p1 = 32x32 transpose, p2/p3 = reversals.
__device__ __forceinline__ int perm_idx(int dir, int i){
  switch (dir) {
    case 0: return i;
    case 1: return ((i & 31) << 5) | (i >> 5);
    case 2: return 1023 - i;
    default: { int j = 1023 - i; return ((j & 31) << 5) | (j >> 5); }
  }
}

// ---------------- router (full batch, reads input x directly) ----------------
__global__ __launch_bounds__(384) void router_mean_kernel(const float* __restrict__ X, float* __restrict__ G){
  int b = blockIdx.y, chunk = blockIdx.x, c = threadIdx.x;
  float s = 0.f;
  const float* xp = X + ((size_t)b*NSEQ + (size_t)chunk*64)*DMODEL + c;
  for (int l = 0; l < 64; ++l) s += xp[(size_t)l*DMODEL];
  atomicAdd(&G[b*DMODEL + c], s * (1.f/1024.f));
}

__global__ __launch_bounds__(96) void router_mlp_kernel(const float* __restrict__ G,
    const float* __restrict__ w1, const float* __restrict__ b1,
    const float* __restrict__ w2, const float* __restrict__ b2, float* __restrict__ WR){
  int b = blockIdx.x, j = threadIdx.x;
  __shared__ float hs[96];
  __shared__ float ls[4];
  float a = b1[j];
  const float* g = G + b*DMODEL;
  for (int c = 0; c < DMODEL; ++c) a += g[c] * w1[j*DMODEL + c];
  hs[j] = 0.5f * a * (1.f + erff(a * 0.70710678118654752f));  // exact gelu
  __syncthreads();
  if (j < 4) {
    float lg = b2[j];
    for (int jj = 0; jj < 96; ++jj) lg += hs[jj] * w2[j*96 + jj];
    ls[j] = lg;
  }
  __syncthreads();
  if (j == 0) {
    float mx = fmaxf(fmaxf(ls[0],ls[1]),fmaxf(ls[2],ls[3]));
    float e0=__expf(ls[0]-mx), e1=__expf(ls[1]-mx), e2=__expf(ls[2]-mx), e3=__expf(ls[3]-mx);
    float s = e0+e1+e2+e3;
    WR[b*4+0]=e0/s; WR[b*4+1]=e1/s; WR[b*4+2]=e2/s; WR[b*4+3]=e3/s;
  }
}

// ---------------- layernorm family (wave64 per 384-row) ----------------
__global__ __launch_bounds__(256) void ln_kernel(const float* __restrict__ X,
    const float* __restrict__ w, const float* __restrict__ bb, float* __restrict__ O){
  int row = blockIdx.x*4 + (threadIdx.x >> 6);
  int lane = threadIdx.x & 63;
  const float* xr = X + (size_t)row*DMODEL;
  float v[6]; float s=0.f, s2=0.f;
  #pragma unroll
  for (int j=0;j<6;++j){ float t = xr[lane + j*64]; v[j]=t; s+=t; s2+=t*t; }
  #pragma unroll
  for (int m=1;m<64;m<<=1){ s += __shfl_xor(s,m,64); s2 += __shfl_xor(s2,m,64); }
  float mu = s*(1.f/DMODEL);
  float rs = rsqrtf(s2*(1.f/DMODEL) - mu*mu + 1e-5f);
  float* o = O + (size_t)row*DMODEL;
  #pragma unroll
  for (int j=0;j<6;++j){ int i = lane+j*64; o[i] = (v[j]-mu)*rs*w[i] + bb[i]; }
}

__global__ __launch_bounds__(256) void ln_final_kernel(const float* __restrict__ XN2,
    const float* __restrict__ AO, const float* __restrict__ gatep,
    const float* __restrict__ w, const float* __restrict__ bb, float* __restrict__ OUT){
  int row = blockIdx.x*4 + (threadIdx.x >> 6);
  int lane = threadIdx.x & 63;
  float gate = gatep[0];
  const float* xr = XN2 + (size_t)row*DMODEL;
  const float* ar = AO + (size_t)row*DMODEL;
  float v[6]; float s=0.f, s2=0.f;
  #pragma unroll
  for (int j=0;j<6;++j){ int i = lane+j*64; float t = xr[i] + gate*ar[i]; v[j]=t; s+=t; s2+=t*t; }
  #pragma unroll
  for (int m=1;m<64;m<<=1){ s += __shfl_xor(s,m,64); s2 += __shfl_xor(s2,m,64); }
  float mu = s*(1.f/DMODEL);
  float rs = rsqrtf(s2*(1.f/DMODEL) - mu*mu + 1e-5f);
  float* o = OUT + (size_t)row*DMODEL;
  #pragma unroll
  for (int j=0;j<6;++j){ int i = lane+j*64; o[i] = (v[j]-mu)*rs*w[i] + bb[i]; }
}

// ---------------- generic f32 GEMM: C[m,n] = act(sum_k A[m,k]*W[n,k] + bias[n]) + resid ----------------
#define GBM 128
#define GBN 128
#define GBK 8
__global__ __launch_bounds__(256) void gemm_kernel(
    const float* __restrict__ A, int lda,
    const float* __restrict__ W, int K, int N,
    const float* __restrict__ bias,
    const float* __restrict__ resid,   // f32 [M x ldc]
    int act,                           // 0 none, 1 softplus
    float* __restrict__ C, int ldc)
{
  __shared__ float As[GBK][GBM+4];
  __shared__ float Ws[GBK][GBN+4];
  const int t = threadIdx.x;
  const int m0 = blockIdx.y * GBM;
  const int n0 = blockIdx.x * GBN;
  const int tx = t & 15, ty = t >> 4;
  const int lrow = t >> 1;
  const int lkq  = (t & 1)*4;
  float acc[8][8];
  #pragma unroll
  for (int i=0;i<8;++i){
    #pragma unroll
    for (int j=0;j<8;++j) acc[i][j]=0.f;
  }
  for (int k0 = 0; k0 < K; k0 += GBK) {
    float4 av = *(const float4*)(A + (size_t)(m0+lrow)*lda + k0 + lkq);
    float4 wv = {0.f,0.f,0.f,0.f};
    {
      int n = n0 + lrow;
      if (n < N) wv = *(const float4*)(W + (size_t)n*K + k0 + lkq);
    }
    __syncthreads();
    As[lkq+0][lrow]=av.x; As[lkq+1][lrow]=av.y; As[lkq+2][lrow]=av.z; As[lkq+3][lrow]=av.w;
    Ws[lkq+0][lrow]=wv.x; Ws[lkq+1][lrow]=wv.y; Ws[lkq+2][lrow]=wv.z; Ws[lkq+3][lrow]=wv.w;
    __syncthreads();
    #pragma unroll
    for (int kk=0;kk<GBK;++kk){
      float4 a0 = *(const float4*)&As[kk][ty*8];
      float4 a1 = *(const float4*)&As[kk][ty*8+4];
      float4 b0 = *(const float4*)&Ws[kk][tx*8];
      float4 b1 = *(const float4*)&Ws[kk][tx*8+4];
      float a[8]={a0.x,a0.y,a0.z,a0.w,a1.x,a1.y,a1.z,a1.w};
      float bb[8]={b0.x,b0.y,b0.z,b0.w,b1.x,b1.y,b1.z,b1.w};
      #pragma unroll
      for (int i=0;i<8;++i){
        #pragma unroll
        for (int j=0;j<8;++j) acc[i][j] += a[i]*bb[j];
      }
    }
  }
  #pragma unroll
  for (int i=0;i<8;++i){
    int m = m0 + ty*8 + i;
    #pragma unroll
    for (int j=0;j<8;++j){
      int n = n0 + tx*8 + j;
      if (n < N){
        float v = acc[i][j];
        if (bias)  v += bias[n];
        if (act == 1) v = (v > 20.f) ? v : log1pf(__expf(v));
        if (resid) v += resid[(size_t)m*ldc + n];
        C[(size_t)m*ldc + n] = v;
      }
    }
  }
}

// ---------------- depthwise causal conv (k=4) over permuted sequence + silu ----------------
__global__ __launch_bounds__(256) void conv_silu_kernel(const float* __restrict__ XZ,
    const float* __restrict__ cw, const float* __restrict__ cb, float* __restrict__ Uo, int dir){
  int idx = blockIdx.x*256 + threadIdx.x;        // (local b)*1024*768 + i*768 + c
  int c = idx % DINNER;
  int rest = idx / DINNER;
  int i = rest & 1023;
  int b = rest >> 10;
  float acc = cb[c];
  #pragma unroll
  for (int k = 0; k < 4; ++k) {
    int ii = i - 3 + k;
    if (ii >= 0)
      acc += cw[c*4 + k] * XZ[((size_t)b*NSEQ + perm_idx(dir, ii))*1536 + c];
  }
  Uo[idx] = acc / (1.f + __expf(-acc));          // silu
}

// ---------------- selective scan: 16 lanes/channel, 4 states/lane, DPP row_ror reduce ----------------
__device__ __forceinline__ float row16_allreduce(float p){
  int t;
  t = __builtin_amdgcn_update_dpp(0, __float_as_int(p), 0x128, 0xf, 0xf, true); p += __int_as_float(t); // ror 8
  t = __builtin_amdgcn_update_dpp(0, __float_as_int(p), 0x124, 0xf, 0xf, true); p += __int_as_float(t); // ror 4
  t = __builtin_amdgcn_update_dpp(0, __float_as_int(p), 0x122, 0xf, 0xf, true); p += __int_as_float(t); // ror 2
  t = __builtin_amdgcn_update_dpp(0, __float_as_int(p), 0x121, 0xf, 0xf, true); p += __int_as_float(t); // ror 1
  return p;
}

__global__ __launch_bounds__(256) void scan_kernel(
    const float* __restrict__ XDBL, const float* __restrict__ DT,
    const float* __restrict__ U, const float* __restrict__ XZ,
    const float* __restrict__ A_log, const float* __restrict__ Dskip,
    const float* __restrict__ WR, float* __restrict__ SACC, int dir, int b0)
{
  const int b = blockIdx.y;                       // local batch within slice
  const int lane = threadIdx.x & 63;
  const int wave = threadIdx.x >> 6;
  const int grp = lane >> 4;
  const int q   = lane & 15;
  const int c = blockIdx.x*16 + wave*4 + grp;
  float A0,A1,A2,A3;
  {
    const float* al = A_log + c*DSTATE + q*4;
    A0 = -__expf(al[0]); A1 = -__expf(al[1]);
    A2 = -__expf(al[2]); A3 = -__expf(al[3]);
  }
  const float dsk = Dskip[c];
  const float wgt = WR[(b0 + b)*4 + dir];
  const size_t rb = (size_t)b * NSEQ;
  float h0=0.f,h1=0.f,h2=0.f,h3=0.f;
  #pragma unroll 4
  for (int l = 0; l < NSEQ; ++l) {
    size_t row = rb + l;
    const float* bc = XDBL + row*XW;
    float4 Bv = *(const float4*)(bc + 24 + q*4);
    float4 Cv = *(const float4*)(bc + 88 + q*4);
    float dt = DT[row*DINNER + c];
    float uu = U[row*DINNER + c];
    float zz = XZ[(rb + (size_t)perm_idx(dir,l))*1536 + DINNER + c];
    float dtu = dt*uu;
    h0 = __expf(dt*A0)*h0 + dtu*Bv.x;
    h1 = __expf(dt*A1)*h1 + dtu*Bv.y;
    h2 = __expf(dt*A2)*h2 + dtu*Bv.z;
    h3 = __expf(dt*A3)*h3 + dtu*Bv.w;
    float p = h0*Cv.x + h1*Cv.y + h2*Cv.z + h3*Cv.w;
    p = row16_allreduce(p);
    if (q == 0) {
      float sz = zz / (1.f + __expf(-zz));       // silu(z)
      size_t oi = row*DINNER + c;                // unique writer per (row,c); dirs serialized
      SACC[oi] += wgt * (p + uu*dsk) * sz;
    }
  }
}

// ---------------- windowed attention (W=4, heads=4, hd=96) ----------------
__global__ __launch_bounds__(256) void attn_kernel(const float* __restrict__ QKV, float* __restrict__ O){
  int idx = blockIdx.x*256 + threadIdx.x;        // (R/4 windows)*4 heads*4 q = 4R threads
  int tq = idx & 3, h = (idx >> 2) & 3, w = idx >> 4;
  size_t row0 = (size_t)w * 4;
  const float4* qp = (const float4*)(QKV + (row0 + tq)*1152 + h*96);
  float sc[4];
  #pragma unroll
  for (int tk = 0; tk < 4; ++tk) {
    const float4* kp = (const float4*)(QKV + (row0 + tk)*1152 + 384 + h*96);
    float d = 0.f;
    #pragma unroll
    for (int j = 0; j < 24; ++j) {
      float4 qf = qp[j], kf = kp[j];
      d += qf.x*kf.x + qf.y*kf.y + qf.z*kf.z + qf.w*kf.w;
    }
    sc[tk] = d * 0.10206207261596575f;           // 1/sqrt(96)
  }
  float mx = fmaxf(fmaxf(sc[0],sc[1]),fmaxf(sc[2],sc[3]));
  float s = 0.f;
  #pragma unroll
  for (int tk=0;tk<4;++tk){ sc[tk]=__expf(sc[tk]-mx); s+=sc[tk]; }
  float inv = 1.f/s;
  #pragma unroll
  for (int tk=0;tk<4;++tk) sc[tk]*=inv;
  float4* op = (float4*)(O + (row0 + tq)*DMODEL + h*96);
  #pragma unroll 4
  for (int j = 0; j < 24; ++j) {
    float4 o = {0.f,0.f,0.f,0.f};
    #pragma unroll
    for (int tk=0;tk<4;++tk){
      const float4* vp = (const float4*)(QKV + (row0+tk)*1152 + 768 + h*96);
      float4 vf = vp[j];
      o.x += sc[tk]*vf.x; o.y += sc[tk]*vf.y; o.z += sc[tk]*vf.z; o.w += sc[tk]*vf.w;
    }
    op[j] = o;
  }
}

extern "C" void kernel_launch(void* const* d_in, const int* in_sizes, int n_in,
                              void* d_out, int out_size, void* d_ws, size_t ws_size,
                              hipStream_t stream)
{
  (void)in_sizes; (void)n_in; (void)out_size;
  const float* x         = (const float*)d_in[0];
  const float* r_w1      = (const float*)d_in[1];
  const float* r_b1      = (const float*)d_in[2];
  const float* r_w2      = (const float*)d_in[3];
  const float* r_b2      = (const float*)d_in[4];
  const float* ln1_w     = (const float*)d_in[5];
  const float* ln1_b     = (const float*)d_in[6];
  const float* ln2_w     = (const float*)d_in[7];
  const float* ln2_b     = (const float*)d_in[8];
  const float* in_proj_w = (const float*)d_in[9];
  const float* conv_w    = (const float*)d_in[10];
  const float* conv_b    = (const float*)d_in[11];
  const float* x_proj_w  = (const float*)d_in[12];
  const float* dt_proj_w = (const float*)d_in[13];
  const float* dt_proj_b = (const float*)d_in[14];
  const float* A_log     = (const float*)d_in[15];
  const float* D_skip    = (const float*)d_in[16];
  const float* out_proj_w= (const float*)d_in[17];
  const float* qkv_w     = (const float*)d_in[18];
  const float* qkv_b     = (const float*)d_in[19];
  const float* ao_w      = (const float*)d_in[20];
  const float* ao_b      = (const float*)d_in[21];
  const float* gate      = (const float*)d_in[22];
  const float* lng_w     = (const float*)d_in[23];
  const float* lng_b     = (const float*)d_in[24];

  float* ws = (float*)d_ws;
  float* WR = ws;            // 32 floats
  float* G  = ws + 64;       // 3072 floats

  // pick largest batch-slice BS in {8,4,2,1} fitting ws_size
  int BS = 8;
  while (BS > 1) {
    size_t need = ((size_t)4096 + (size_t)BS*1024*4376) * sizeof(float);
    if (need <= ws_size) break;
    BS >>= 1;
  }
  const int R = BS * 1024;   // rows per slice

  hipMemsetAsync(ws, 0, 4096*sizeof(float), stream);      // WR + G
  router_mean_kernel<<<dim3(16,8),384,0,stream>>>(x, G);
  router_mlp_kernel<<<8,96,0,stream>>>(G, r_w1, r_b1, r_w2, r_b2, WR);

  float* base = ws + 4096;
  float* XN   = base;                 // R*384
  float* XZ   = XN   + (size_t)R*384; // R*1536
  float* Ub   = XZ   + (size_t)R*1536;// R*768
  float* XDBL = Ub   + (size_t)R*768; // R*152
  float* DTb  = XDBL + (size_t)R*152; // R*768
  float* SACC = DTb  + (size_t)R*768; // R*768
  // reuse after lifetimes end:
  float* X2   = XN;    // out_proj output (R*384)
  float* XN2  = SACC;  // ln2 output (R*384 <= R*768)
  float* QKV  = XZ;    // qkv output (R*1152 <= R*1536)
  float* ATTO = Ub;    // attn output (R*384)
  float* AOb  = DTb;   // ao output (R*384)

  for (int s = 0; s < 8/BS; ++s) {
    const int b0 = s * BS;
    const size_t xoff = (size_t)b0 * NSEQ * DMODEL;

    hipMemsetAsync(SACC, 0, (size_t)R*768*sizeof(float), stream);
    ln_kernel<<<R/4,256,0,stream>>>(x + xoff, ln1_w, ln1_b, XN);
    // in_proj once per slice (row-permutations commute with row-wise linear)
    gemm_kernel<<<dim3(12,R/128),256,0,stream>>>(XN,384, in_proj_w,384,1536, nullptr,nullptr,0, XZ,1536);
    for (int dir = 0; dir < 4; ++dir) {
      conv_silu_kernel<<<3*R,256,0,stream>>>(XZ, conv_w, conv_b, Ub, dir);
      gemm_kernel<<<dim3(2,R/128),256,0,stream>>>(Ub,768, x_proj_w,768,152, nullptr,nullptr,0, XDBL,152);
      gemm_kernel<<<dim3(6,R/128),256,0,stream>>>(XDBL,152, dt_proj_w,24,768, dt_proj_b,nullptr,1, DTb,768);
      scan_kernel<<<dim3(48,BS),256,0,stream>>>(XDBL, DTb, Ub, XZ, A_log, D_skip, WR, SACC, dir, b0);
    }
    // fused = (sum_d w_d * gated_d) @ out_proj^T ; + x residual
    gemm_kernel<<<dim3(3,R/128),256,0,stream>>>(SACC,768, out_proj_w,768,384, nullptr,x + xoff,0, X2,384);
    ln_kernel<<<R/4,256,0,stream>>>(X2, ln2_w, ln2_b, XN2);
    gemm_kernel<<<dim3(9,R/128),256,0,stream>>>(XN2,384, qkv_w,384,1152, qkv_b,nullptr,0, QKV,1152);
    attn_kernel<<<R/64,256,0,stream>>>(QKV, ATTO);                       // 4R threads exactly
    gemm_kernel<<<dim3(3,R/128),256,0,stream>>>(ATTO,384, ao_w,384,384, ao_b,nullptr,0, AOb,384);
    ln_final_kernel<<<R/4,256,0,stream>>>(XN2, AOb, gate, lng_w, lng_b, (float*)d_out + xoff);
  }
}

// Round 4
// 3330.579 us; speedup vs baseline: 1.4237x; 1.4237x over previous
//
#include <hip/hip_runtime.h>
#include <math.h>

// ASMambaBlock: router + 4-direction Mamba (selective scan) + windowed MHA.
// All tensors float32. Internal f32 in d_ws. Batch-sliced: per-slice floats =
// 4096 + R*4376, R = BS*1024, BS = largest of {8,4,2,1} fitting ws_size.

#define NSEQ  1024
#define DMODEL 384
#define DINNER 768
#define DSTATE 64
#define XW 152            // dt_rank(24) + 2*d_state(128)

// PERMS closed-form: side=32. p1 = 32x32 transpose, p2/p3 = reversals.
template<int DIR>
__device__ __forceinline__ int permi(int i){
  if (DIR == 0) return i;
  if (DIR == 1) return ((i & 31) << 5) | (i >> 5);
  if (DIR == 2) return 1023 - i;
  int j = 1023 - i; return ((j & 31) << 5) | (j >> 5);
}

// ---------------- router ----------------
__global__ __launch_bounds__(384) void router_mean_kernel(const float* __restrict__ X, float* __restrict__ G){
  int b = blockIdx.y, chunk = blockIdx.x, c = threadIdx.x;
  float s = 0.f;
  const float* xp = X + ((size_t)b*NSEQ + (size_t)chunk*64)*DMODEL + c;
  for (int l = 0; l < 64; ++l) s += xp[(size_t)l*DMODEL];
  atomicAdd(&G[b*DMODEL + c], s * (1.f/1024.f));
}

__global__ __launch_bounds__(96) void router_mlp_kernel(const float* __restrict__ G,
    const float* __restrict__ w1, const float* __restrict__ b1,
    const float* __restrict__ w2, const float* __restrict__ b2, float* __restrict__ WR){
  int b = blockIdx.x, j = threadIdx.x;
  __shared__ float hs[96];
  __shared__ float ls[4];
  float a = b1[j];
  const float* g = G + b*DMODEL;
  for (int c = 0; c < DMODEL; ++c) a += g[c] * w1[j*DMODEL + c];
  hs[j] = 0.5f * a * (1.f + erff(a * 0.70710678118654752f));  // exact gelu
  __syncthreads();
  if (j < 4) {
    float lg = b2[j];
    for (int jj = 0; jj < 96; ++jj) lg += hs[jj] * w2[j*96 + jj];
    ls[j] = lg;
  }
  __syncthreads();
  if (j == 0) {
    float mx = fmaxf(fmaxf(ls[0],ls[1]),fmaxf(ls[2],ls[3]));
    float e0=__expf(ls[0]-mx), e1=__expf(ls[1]-mx), e2=__expf(ls[2]-mx), e3=__expf(ls[3]-mx);
    float s = e0+e1+e2+e3;
    WR[b*4+0]=e0/s; WR[b*4+1]=e1/s; WR[b*4+2]=e2/s; WR[b*4+3]=e3/s;
  }
}

// ---------------- layernorm family (wave64 per 384-row) ----------------
__global__ __launch_bounds__(256) void ln_kernel(const float* __restrict__ X,
    const float* __restrict__ w, const float* __restrict__ bb, float* __restrict__ O){
  int row = blockIdx.x*4 + (threadIdx.x >> 6);
  int lane = threadIdx.x & 63;
  const float* xr = X + (size_t)row*DMODEL;
  float v[6]; float s=0.f, s2=0.f;
  #pragma unroll
  for (int j=0;j<6;++j){ float t = xr[lane + j*64]; v[j]=t; s+=t; s2+=t*t; }
  #pragma unroll
  for (int m=1;m<64;m<<=1){ s += __shfl_xor(s,m,64); s2 += __shfl_xor(s2,m,64); }
  float mu = s*(1.f/DMODEL);
  float rs = rsqrtf(s2*(1.f/DMODEL) - mu*mu + 1e-5f);
  float* o = O + (size_t)row*DMODEL;
  #pragma unroll
  for (int j=0;j<6;++j){ int i = lane+j*64; o[i] = (v[j]-mu)*rs*w[i] + bb[i]; }
}

__global__ __launch_bounds__(256) void ln_final_kernel(const float* __restrict__ XN2,
    const float* __restrict__ AO, const float* __restrict__ gatep,
    const float* __restrict__ w, const float* __restrict__ bb, float* __restrict__ OUT){
  int row = blockIdx.x*4 + (threadIdx.x >> 6);
  int lane = threadIdx.x & 63;
  float gate = gatep[0];
  const float* xr = XN2 + (size_t)row*DMODEL;
  const float* ar = AO + (size_t)row*DMODEL;
  float v[6]; float s=0.f, s2=0.f;
  #pragma unroll
  for (int j=0;j<6;++j){ int i = lane+j*64; float t = xr[i] + gate*ar[i]; v[j]=t; s+=t; s2+=t*t; }
  #pragma unroll
  for (int m=1;m<64;m<<=1){ s += __shfl_xor(s,m,64); s2 += __shfl_xor(s2,m,64); }
  float mu = s*(1.f/DMODEL);
  float rs = rsqrtf(s2*(1.f/DMODEL) - mu*mu + 1e-5f);
  float* o = OUT + (size_t)row*DMODEL;
  #pragma unroll
  for (int j=0;j<6;++j){ int i = lane+j*64; o[i] = (v[j]-mu)*rs*w[i] + bb[i]; }
}

// ---------------- generic f32 GEMM: C[m,n] = act(sum_k A[m,k]*W[n,k] + bias[n]) + resid ----------------
#define GBM 128
#define GBN 128
#define GBK 8
__global__ __launch_bounds__(256) void gemm_kernel(
    const float* __restrict__ A, int lda,
    const float* __restrict__ W, int K, int N,
    const float* __restrict__ bias,
    const float* __restrict__ resid,   // f32 [M x ldc]
    int act,                           // 0 none, 1 softplus
    float* __restrict__ C, int ldc)
{
  __shared__ float As[GBK][GBM+4];
  __shared__ float Ws[GBK][GBN+4];
  const int t = threadIdx.x;
  const int m0 = blockIdx.y * GBM;
  const int n0 = blockIdx.x * GBN;
  const int tx = t & 15, ty = t >> 4;
  const int lrow = t >> 1;
  const int lkq  = (t & 1)*4;
  float acc[8][8];
  #pragma unroll
  for (int i=0;i<8;++i){
    #pragma unroll
    for (int j=0;j<8;++j) acc[i][j]=0.f;
  }
  for (int k0 = 0; k0 < K; k0 += GBK) {
    float4 av = *(const float4*)(A + (size_t)(m0+lrow)*lda + k0 + lkq);
    float4 wv = {0.f,0.f,0.f,0.f};
    {
      int n = n0 + lrow;
      if (n < N) wv = *(const float4*)(W + (size_t)n*K + k0 + lkq);
    }
    __syncthreads();
    As[lkq+0][lrow]=av.x; As[lkq+1][lrow]=av.y; As[lkq+2][lrow]=av.z; As[lkq+3][lrow]=av.w;
    Ws[lkq+0][lrow]=wv.x; Ws[lkq+1][lrow]=wv.y; Ws[lkq+2][lrow]=wv.z; Ws[lkq+3][lrow]=wv.w;
    __syncthreads();
    #pragma unroll
    for (int kk=0;kk<GBK;++kk){
      float4 a0 = *(const float4*)&As[kk][ty*8];
      float4 a1 = *(const float4*)&As[kk][ty*8+4];
      float4 b0 = *(const float4*)&Ws[kk][tx*8];
      float4 b1 = *(const float4*)&Ws[kk][tx*8+4];
      float a[8]={a0.x,a0.y,a0.z,a0.w,a1.x,a1.y,a1.z,a1.w};
      float bb[8]={b0.x,b0.y,b0.z,b0.w,b1.x,b1.y,b1.z,b1.w};
      #pragma unroll
      for (int i=0;i<8;++i){
        #pragma unroll
        for (int j=0;j<8;++j) acc[i][j] += a[i]*bb[j];
      }
    }
  }
  #pragma unroll
  for (int i=0;i<8;++i){
    int m = m0 + ty*8 + i;
    #pragma unroll
    for (int j=0;j<8;++j){
      int n = n0 + tx*8 + j;
      if (n < N){
        float v = acc[i][j];
        if (bias)  v += bias[n];
        if (act == 1) v = (v > 20.f) ? v : log1pf(__expf(v));
        if (resid) v += resid[(size_t)m*ldc + n];
        C[(size_t)m*ldc + n] = v;
      }
    }
  }
}

// ---------------- in-place silu on the z-half of XZ (once, shared by 4 dirs) ----------------
__global__ __launch_bounds__(256) void zsilu_kernel(float* __restrict__ XZ){
  int idx = blockIdx.x*256 + threadIdx.x;       // R*192 threads, float4 each
  int row = idx / 192, q = idx % 192;
  float4* p = (float4*)(XZ + (size_t)row*1536 + DINNER + q*4);
  float4 v = *p;
  v.x = v.x / (1.f + __expf(-v.x));
  v.y = v.y / (1.f + __expf(-v.y));
  v.z = v.z / (1.f + __expf(-v.z));
  v.w = v.w / (1.f + __expf(-v.w));
  *p = v;
}

// ---------------- depthwise causal conv (k=4) over permuted sequence + silu ----------------
template<int DIR>
__global__ __launch_bounds__(256) void conv_silu_kernel(const float* __restrict__ XZ,
    const float* __restrict__ cw, const float* __restrict__ cb, float* __restrict__ Uo){
  int idx = blockIdx.x*256 + threadIdx.x;        // (local b)*1024*768 + i*768 + c
  int c = idx % DINNER;
  int rest = idx / DINNER;
  int i = rest & 1023;
  int b = rest >> 10;
  float acc = cb[c];
  #pragma unroll
  for (int k = 0; k < 4; ++k) {
    int ii = i - 3 + k;
    if (ii >= 0)
      acc += cw[c*4 + k] * XZ[((size_t)b*NSEQ + permi<DIR>(ii))*1536 + c];
  }
  Uo[idx] = acc / (1.f + __expf(-acc));          // silu
}

// ---------------- selective scan: 1 wave per (b,c), 64 states (1/lane) ----------------
__device__ __forceinline__ float wave64_reduce(float p){
  int t;
  t = __builtin_amdgcn_update_dpp(0, __float_as_int(p), 0x128, 0xf, 0xf, true); p += __int_as_float(t); // row_ror 8
  t = __builtin_amdgcn_update_dpp(0, __float_as_int(p), 0x124, 0xf, 0xf, true); p += __int_as_float(t); // row_ror 4
  t = __builtin_amdgcn_update_dpp(0, __float_as_int(p), 0x122, 0xf, 0xf, true); p += __int_as_float(t); // row_ror 2
  t = __builtin_amdgcn_update_dpp(0, __float_as_int(p), 0x121, 0xf, 0xf, true); p += __int_as_float(t); // row_ror 1
  p += __shfl_xor(p, 16, 64);
  p += __shfl_xor(p, 32, 64);
  return p;
}

// per-step register set loaded PDIST steps ahead (rotation-4 pipeline, no copies)
template<int DIR>
__global__ __launch_bounds__(256) void scan_kernel(
    const float* __restrict__ XDBL, const float* __restrict__ DT,
    const float* __restrict__ U, const float* __restrict__ XZ,  // z-half pre-silu'd in place
    const float* __restrict__ A_log, const float* __restrict__ Dskip,
    const float* __restrict__ WR, float* __restrict__ SACC, int b0)
{
  const int b = blockIdx.y;
  const int lane = threadIdx.x & 63;
  const int wave = threadIdx.x >> 6;
  const int c = blockIdx.x*4 + wave;              // 0..767
  const float As  = -__expf(A_log[c*DSTATE + lane]);
  const float dsk = Dskip[c];
  const float wgt = WR[(b0 + b)*4 + DIR];
  const size_t rb = (size_t)b * NSEQ;
  const float* xd  = XDBL + rb*XW;
  const float* dtp = DT + rb*DINNER + c;
  const float* up  = U  + rb*DINNER + c;
  const float* zp  = XZ + rb*1536 + DINNER + c;   // + perm(l)*1536
  float* sp = SACC + rb*DINNER + c;

  // load register set k for step l (clamped; tail garbage never consumed)
#define SLOAD(k, l) { int lr = (l) < 1023 ? (l) : 1023;                  \
    const float* x2 = xd + (size_t)lr*XW;                                \
    B##k = x2[24+lane]; C##k = x2[88+lane];                              \
    d##k = dtp[(size_t)lr*DINNER]; u##k = up[(size_t)lr*DINNER];         \
    z##k = zp[(size_t)permi<DIR>(lr)*1536]; }
#define SSTEP(k, l) {                                                    \
    float e = __expf(d##k * As);                                         \
    float dtu = d##k * u##k;                                             \
    h = e*h + dtu*B##k;                                                  \
    float p = wave64_reduce(h * C##k);                                   \
    if (lane == 0) sp[(size_t)(l)*DINNER] += wgt*(p + u##k*dsk)*z##k; }

  float B0,C0,d0,u0,z0, B1,C1,d1,u1,z1, B2,C2,d2,u2,z2, B3,C3,d3,u3,z3;
  float h = 0.f;
  SLOAD(0,0) SLOAD(1,1) SLOAD(2,2) SLOAD(3,3)
  for (int l = 0; l < NSEQ; l += 4) {
    SSTEP(0,l)   SLOAD(0,l+4)
    SSTEP(1,l+1) SLOAD(1,l+5)
    SSTEP(2,l+2) SLOAD(2,l+6)
    SSTEP(3,l+3) SLOAD(3,l+7)
  }
#undef SLOAD
#undef SSTEP
}

// ---------------- windowed attention (W=4, heads=4, hd=96) ----------------
__global__ __launch_bounds__(256) void attn_kernel(const float* __restrict__ QKV, float* __restrict__ O){
  int idx = blockIdx.x*256 + threadIdx.x;        // (R/4 windows)*4 heads*4 q = 4R threads
  int tq = idx & 3, h = (idx >> 2) & 3, w = idx >> 4;
  size_t row0 = (size_t)w * 4;
  const float4* qp = (const float4*)(QKV + (row0 + tq)*1152 + h*96);
  float sc[4];
  #pragma unroll
  for (int tk = 0; tk < 4; ++tk) {
    const float4* kp = (const float4*)(QKV + (row0 + tk)*1152 + 384 + h*96);
    float d = 0.f;
    #pragma unroll
    for (int j = 0; j < 24; ++j) {
      float4 qf = qp[j], kf = kp[j];
      d += qf.x*kf.x + qf.y*kf.y + qf.z*kf.z + qf.w*kf.w;
    }
    sc[tk] = d * 0.10206207261596575f;           // 1/sqrt(96)
  }
  float mx = fmaxf(fmaxf(sc[0],sc[1]),fmaxf(sc[2],sc[3]));
  float s = 0.f;
  #pragma unroll
  for (int tk=0;tk<4;++tk){ sc[tk]=__expf(sc[tk]-mx); s+=sc[tk]; }
  float inv = 1.f/s;
  #pragma unroll
  for (int tk=0;tk<4;++tk) sc[tk]*=inv;
  float4* op = (float4*)(O + (row0 + tq)*DMODEL + h*96);
  #pragma unroll 4
  for (int j = 0; j < 24; ++j) {
    float4 o = {0.f,0.f,0.f,0.f};
    #pragma unroll
    for (int tk=0;tk<4;++tk){
      const float4* vp = (const float4*)(QKV + (row0+tk)*1152 + 768 + h*96);
      float4 vf = vp[j];
      o.x += sc[tk]*vf.x; o.y += sc[tk]*vf.y; o.z += sc[tk]*vf.z; o.w += sc[tk]*vf.w;
    }
    op[j] = o;
  }
}

extern "C" void kernel_launch(void* const* d_in, const int* in_sizes, int n_in,
                              void* d_out, int out_size, void* d_ws, size_t ws_size,
                              hipStream_t stream)
{
  (void)in_sizes; (void)n_in; (void)out_size;
  const float* x         = (const float*)d_in[0];
  const float* r_w1      = (const float*)d_in[1];
  const float* r_b1      = (const float*)d_in[2];
  const float* r_w2      = (const float*)d_in[3];
  const float* r_b2      = (const float*)d_in[4];
  const float* ln1_w     = (const float*)d_in[5];
  const float* ln1_b     = (const float*)d_in[6];
  const float* ln2_w     = (const float*)d_in[7];
  const float* ln2_b     = (const float*)d_in[8];
  const float* in_proj_w = (const float*)d_in[9];
  const float* conv_w    = (const float*)d_in[10];
  const float* conv_b    = (const float*)d_in[11];
  const float* x_proj_w  = (const float*)d_in[12];
  const float* dt_proj_w = (const float*)d_in[13];
  const float* dt_proj_b = (const float*)d_in[14];
  const float* A_log     = (const float*)d_in[15];
  const float* D_skip    = (const float*)d_in[16];
  const float* out_proj_w= (const float*)d_in[17];
  const float* qkv_w     = (const float*)d_in[18];
  const float* qkv_b     = (const float*)d_in[19];
  const float* ao_w      = (const float*)d_in[20];
  const float* ao_b      = (const float*)d_in[21];
  const float* gate      = (const float*)d_in[22];
  const float* lng_w     = (const float*)d_in[23];
  const float* lng_b     = (const float*)d_in[24];

  float* ws = (float*)d_ws;
  float* WR = ws;            // 32 floats
  float* G  = ws + 64;       // 3072 floats

  int BS = 8;
  while (BS > 1) {
    size_t need = ((size_t)4096 + (size_t)BS*1024*4376) * sizeof(float);
    if (need <= ws_size) break;
    BS >>= 1;
  }
  const int R = BS * 1024;   // rows per slice

  hipMemsetAsync(ws, 0, 4096*sizeof(float), stream);      // WR + G
  router_mean_kernel<<<dim3(16,8),384,0,stream>>>(x, G);
  router_mlp_kernel<<<8,96,0,stream>>>(G, r_w1, r_b1, r_w2, r_b2, WR);

  float* base = ws + 4096;
  float* XN   = base;                 // R*384
  float* XZ   = XN   + (size_t)R*384; // R*1536
  float* Ub   = XZ   + (size_t)R*1536;// R*768
  float* XDBL = Ub   + (size_t)R*768; // R*152
  float* DTb  = XDBL + (size_t)R*152; // R*768
  float* SACC = DTb  + (size_t)R*768; // R*768
  float* X2   = XN;    // out_proj output (R*384)
  float* XN2  = SACC;  // ln2 output
  float* QKV  = XZ;    // qkv output (R*1152 <= R*1536)
  float* ATTO = Ub;    // attn output
  float* AOb  = DTb;   // ao output

  for (int s = 0; s < 8/BS; ++s) {
    const int b0 = s * BS;
    const size_t xoff = (size_t)b0 * NSEQ * DMODEL;

    hipMemsetAsync(SACC, 0, (size_t)R*768*sizeof(float), stream);
    ln_kernel<<<R/4,256,0,stream>>>(x + xoff, ln1_w, ln1_b, XN);
    gemm_kernel<<<dim3(12,R/128),256,0,stream>>>(XN,384, in_proj_w,384,1536, nullptr,nullptr,0, XZ,1536);
    zsilu_kernel<<<(R*192)/256,256,0,stream>>>(XZ);   // silu(z) once, in place
    for (int dir = 0; dir < 4; ++dir) {
      switch (dir) {
        case 0: conv_silu_kernel<0><<<3*R,256,0,stream>>>(XZ, conv_w, conv_b, Ub); break;
        case 1: conv_silu_kernel<1><<<3*R,256,0,stream>>>(XZ, conv_w, conv_b, Ub); break;
        case 2: conv_silu_kernel<2><<<3*R,256,0,stream>>>(XZ, conv_w, conv_b, Ub); break;
        default: conv_silu_kernel<3><<<3*R,256,0,stream>>>(XZ, conv_w, conv_b, Ub); break;
      }
      gemm_kernel<<<dim3(2,R/128),256,0,stream>>>(Ub,768, x_proj_w,768,152, nullptr,nullptr,0, XDBL,152);
      gemm_kernel<<<dim3(6,R/128),256,0,stream>>>(XDBL,152, dt_proj_w,24,768, dt_proj_b,nullptr,1, DTb,768);
      switch (dir) {
        case 0: scan_kernel<0><<<dim3(192,BS),256,0,stream>>>(XDBL, DTb, Ub, XZ, A_log, D_skip, WR, SACC, b0); break;
        case 1: scan_kernel<1><<<dim3(192,BS),256,0,stream>>>(XDBL, DTb, Ub, XZ, A_log, D_skip, WR, SACC, b0); break;
        case 2: scan_kernel<2><<<dim3(192,BS),256,0,stream>>>(XDBL, DTb, Ub, XZ, A_log, D_skip, WR, SACC, b0); break;
        default: scan_kernel<3><<<dim3(192,BS),256,0,stream>>>(XDBL, DTb, Ub, XZ, A_log, D_skip, WR, SACC, b0); break;
      }
    }
    gemm_kernel<<<dim3(3,R/128),256,0,stream>>>(SACC,768, out_proj_w,768,384, nullptr,x + xoff,0, X2,384);
    ln_kernel<<<R/4,256,0,stream>>>(X2, ln2_w, ln2_b, XN2);
    gemm_kernel<<<dim3(9,R/128),256,0,stream>>>(XN2,384, qkv_w,384,1152, qkv_b,nullptr,0, QKV,1152);
    attn_kernel<<<R/64,256,0,stream>>>(QKV, ATTO);
    gemm_kernel<<<dim3(3,R/128),256,0,stream>>>(ATTO,384, ao_w,384,384, ao_b,nullptr,0, AOb,384);
    ln_final_kernel<<<R/4,256,0,stream>>>(XN2, AOb, gate, lng_w, lng_b, (float*)d_out + xoff);
  }
}

// Round 6
// 2868.783 us; speedup vs baseline: 1.6529x; 1.1610x over previous
//
#include <hip/hip_runtime.h>
#include <math.h>

// ASMambaBlock: router + 4-direction Mamba (selective scan) + windowed MHA.
// All tensors float32. Internal f32 in d_ws. Batch-sliced: per-slice floats =
// 4096 + R*4376, R = BS*1024, BS = largest of {8,4,2,1} fitting ws_size.

#define NSEQ  1024
#define DMODEL 384
#define DINNER 768
#define DSTATE 64
#define XW 152            // dt_rank(24) + 2*d_state(128)

// PERMS closed-form: side=32. p1 = 32x32 transpose, p2/p3 = reversals.
template<int DIR>
__device__ __forceinline__ int permi(int i){
  if (DIR == 0) return i;
  if (DIR == 1) return ((i & 31) << 5) | (i >> 5);
  if (DIR == 2) return 1023 - i;
  int j = 1023 - i; return ((j & 31) << 5) | (j >> 5);
}

// ---------------- router ----------------
__global__ __launch_bounds__(384) void router_mean_kernel(const float* __restrict__ X, float* __restrict__ G){
  int b = blockIdx.y, chunk = blockIdx.x, c = threadIdx.x;
  float s = 0.f;
  const float* xp = X + ((size_t)b*NSEQ + (size_t)chunk*64)*DMODEL + c;
  for (int l = 0; l < 64; ++l) s += xp[(size_t)l*DMODEL];
  atomicAdd(&G[b*DMODEL + c], s * (1.f/1024.f));
}

__global__ __launch_bounds__(96) void router_mlp_kernel(const float* __restrict__ G,
    const float* __restrict__ w1, const float* __restrict__ b1,
    const float* __restrict__ w2, const float* __restrict__ b2, float* __restrict__ WR){
  int b = blockIdx.x, j = threadIdx.x;
  __shared__ float hs[96];
  __shared__ float ls[4];
  float a = b1[j];
  const float* g = G + b*DMODEL;
  for (int c = 0; c < DMODEL; ++c) a += g[c] * w1[j*DMODEL + c];
  hs[j] = 0.5f * a * (1.f + erff(a * 0.70710678118654752f));  // exact gelu
  __syncthreads();
  if (j < 4) {
    float lg = b2[j];
    for (int jj = 0; jj < 96; ++jj) lg += hs[jj] * w2[j*96 + jj];
    ls[j] = lg;
  }
  __syncthreads();
  if (j == 0) {
    float mx = fmaxf(fmaxf(ls[0],ls[1]),fmaxf(ls[2],ls[3]));
    float e0=__expf(ls[0]-mx), e1=__expf(ls[1]-mx), e2=__expf(ls[2]-mx), e3=__expf(ls[3]-mx);
    float s = e0+e1+e2+e3;
    WR[b*4+0]=e0/s; WR[b*4+1]=e1/s; WR[b*4+2]=e2/s; WR[b*4+3]=e3/s;
  }
}

// ---------------- layernorm family (wave64 per 384-row) ----------------
__global__ __launch_bounds__(256) void ln_kernel(const float* __restrict__ X,
    const float* __restrict__ w, const float* __restrict__ bb, float* __restrict__ O){
  int row = blockIdx.x*4 + (threadIdx.x >> 6);
  int lane = threadIdx.x & 63;
  const float* xr = X + (size_t)row*DMODEL;
  float v[6]; float s=0.f, s2=0.f;
  #pragma unroll
  for (int j=0;j<6;++j){ float t = xr[lane + j*64]; v[j]=t; s+=t; s2+=t*t; }
  #pragma unroll
  for (int m=1;m<64;m<<=1){ s += __shfl_xor(s,m,64); s2 += __shfl_xor(s2,m,64); }
  float mu = s*(1.f/DMODEL);
  float rs = rsqrtf(s2*(1.f/DMODEL) - mu*mu + 1e-5f);
  float* o = O + (size_t)row*DMODEL;
  #pragma unroll
  for (int j=0;j<6;++j){ int i = lane+j*64; o[i] = (v[j]-mu)*rs*w[i] + bb[i]; }
}

__global__ __launch_bounds__(256) void ln_final_kernel(const float* __restrict__ XN2,
    const float* __restrict__ AO, const float* __restrict__ gatep,
    const float* __restrict__ w, const float* __restrict__ bb, float* __restrict__ OUT){
  int row = blockIdx.x*4 + (threadIdx.x >> 6);
  int lane = threadIdx.x & 63;
  float gate = gatep[0];
  const float* xr = XN2 + (size_t)row*DMODEL;
  const float* ar = AO + (size_t)row*DMODEL;
  float v[6]; float s=0.f, s2=0.f;
  #pragma unroll
  for (int j=0;j<6;++j){ int i = lane+j*64; float t = xr[i] + gate*ar[i]; v[j]=t; s+=t; s2+=t*t; }
  #pragma unroll
  for (int m=1;m<64;m<<=1){ s += __shfl_xor(s,m,64); s2 += __shfl_xor(s2,m,64); }
  float mu = s*(1.f/DMODEL);
  float rs = rsqrtf(s2*(1.f/DMODEL) - mu*mu + 1e-5f);
  float* o = OUT + (size_t)row*DMODEL;
  #pragma unroll
  for (int j=0;j<6;++j){ int i = lane+j*64; o[i] = (v[j]-mu)*rs*w[i] + bb[i]; }
}

// ---------------- generic f32 GEMM: C[m,n] = act(sum_k A[m,k]*W[n,k] + bias[n]) + resid ----------------
#define GBM 128
#define GBN 128
#define GBK 8
__global__ __launch_bounds__(256) void gemm_kernel(
    const float* __restrict__ A, int lda,
    const float* __restrict__ W, int K, int N,
    const float* __restrict__ bias,
    const float* __restrict__ resid,   // f32 [M x ldc]
    int act,                           // 0 none, 1 softplus
    float* __restrict__ C, int ldc)
{
  __shared__ float As[GBK][GBM+4];
  __shared__ float Ws[GBK][GBN+4];
  const int t = threadIdx.x;
  const int m0 = blockIdx.y * GBM;
  const int n0 = blockIdx.x * GBN;
  const int tx = t & 15, ty = t >> 4;
  const int lrow = t >> 1;
  const int lkq  = (t & 1)*4;
  float acc[8][8];
  #pragma unroll
  for (int i=0;i<8;++i){
    #pragma unroll
    for (int j=0;j<8;++j) acc[i][j]=0.f;
  }
  for (int k0 = 0; k0 < K; k0 += GBK) {
    float4 av = *(const float4*)(A + (size_t)(m0+lrow)*lda + k0 + lkq);
    float4 wv = {0.f,0.f,0.f,0.f};
    {
      int n = n0 + lrow;
      if (n < N) wv = *(const float4*)(W + (size_t)n*K + k0 + lkq);
    }
    __syncthreads();
    As[lkq+0][lrow]=av.x; As[lkq+1][lrow]=av.y; As[lkq+2][lrow]=av.z; As[lkq+3][lrow]=av.w;
    Ws[lkq+0][lrow]=wv.x; Ws[lkq+1][lrow]=wv.y; Ws[lkq+2][lrow]=wv.z; Ws[lkq+3][lrow]=wv.w;
    __syncthreads();
    #pragma unroll
    for (int kk=0;kk<GBK;++kk){
      float4 a0 = *(const float4*)&As[kk][ty*8];
      float4 a1 = *(const float4*)&As[kk][ty*8+4];
      float4 b0 = *(const float4*)&Ws[kk][tx*8];
      float4 b1 = *(const float4*)&Ws[kk][tx*8+4];
      float a[8]={a0.x,a0.y,a0.z,a0.w,a1.x,a1.y,a1.z,a1.w};
      float bb[8]={b0.x,b0.y,b0.z,b0.w,b1.x,b1.y,b1.z,b1.w};
      #pragma unroll
      for (int i=0;i<8;++i){
        #pragma unroll
        for (int j=0;j<8;++j) acc[i][j] += a[i]*bb[j];
      }
    }
  }
  #pragma unroll
  for (int i=0;i<8;++i){
    int m = m0 + ty*8 + i;
    #pragma unroll
    for (int j=0;j<8;++j){
      int n = n0 + tx*8 + j;
      if (n < N){
        float v = acc[i][j];
        if (bias)  v += bias[n];
        if (act == 1) v = (v > 20.f) ? v : log1pf(__expf(v));
        if (resid) v += resid[(size_t)m*ldc + n];
        C[(size_t)m*ldc + n] = v;
      }
    }
  }
}

// ---------------- in-place silu on the z-half of XZ (once, shared by 4 dirs) ----------------
__global__ __launch_bounds__(256) void zsilu_kernel(float* __restrict__ XZ){
  int idx = blockIdx.x*256 + threadIdx.x;       // R*192 threads, float4 each
  int row = idx / 192, q = idx % 192;
  float4* p = (float4*)(XZ + (size_t)row*1536 + DINNER + q*4);
  float4 v = *p;
  v.x = v.x / (1.f + __expf(-v.x));
  v.y = v.y / (1.f + __expf(-v.y));
  v.z = v.z / (1.f + __expf(-v.z));
  v.w = v.w / (1.f + __expf(-v.w));
  *p = v;
}

// ---------------- depthwise causal conv (k=4) over permuted sequence + silu ----------------
template<int DIR>
__global__ __launch_bounds__(256) void conv_silu_kernel(const float* __restrict__ XZ,
    const float* __restrict__ cw, const float* __restrict__ cb, float* __restrict__ Uo){
  int idx = blockIdx.x*256 + threadIdx.x;        // (local b)*1024*768 + i*768 + c
  int c = idx % DINNER;
  int rest = idx / DINNER;
  int i = rest & 1023;
  int b = rest >> 10;
  float acc = cb[c];
  #pragma unroll
  for (int k = 0; k < 4; ++k) {
    int ii = i - 3 + k;
    if (ii >= 0)
      acc += cw[c*4 + k] * XZ[((size_t)b*NSEQ + permi<DIR>(ii))*1536 + c];
  }
  Uo[idx] = acc / (1.f + __expf(-acc));          // silu
}

// ---------------- selective scan: 1 wave per 4 channels, lane = state ----------------
// All-DPP wave64 reduce: 4x row_ror (row sums) + row_bcast15 + row_bcast31.
// DPP ctrl must be an ICE -> template parameter.
template<int CTRL>
__device__ __forceinline__ float dpp_add(float v){
  int t = __builtin_amdgcn_update_dpp(0, __float_as_int(v), CTRL, 0xf, 0xf, true);
  return v + __int_as_float(t);
}
__device__ __forceinline__ float wave64_reduce_hi(float p){
  p = dpp_add<0x128>(p); // row_ror 8
  p = dpp_add<0x124>(p); // row_ror 4
  p = dpp_add<0x122>(p); // row_ror 2
  p = dpp_add<0x121>(p); // row_ror 1  -> each row of 16 has its sum
  p = dpp_add<0x142>(p); // row_bcast15: row1 += row0, row3 += row2
  p = dpp_add<0x143>(p); // row_bcast31: lanes32-63 += (row0+row1)
  return p;              // lanes 48..63 = total
}

// Rotation-4 software pipeline; per wave: 4 channels (c0..c0+3), lane = state.
// dt/u/z/SACC are wave-uniform float4 loads (full 16B of each 64B line used
// by the block's 4 waves -> no over-fetch); B/C shared across the 4 channels.
template<int DIR>
__global__ __launch_bounds__(64) void scan_kernel(
    const float* __restrict__ XDBL, const float* __restrict__ DT,
    const float* __restrict__ U, const float* __restrict__ XZ,  // z-half pre-silu'd
    const float* __restrict__ A_log, const float* __restrict__ Dskip,
    const float* __restrict__ WR, float* __restrict__ SACC, int b0)
{
  const int b = blockIdx.y;
  const int lane = threadIdx.x;
  const int c0 = blockIdx.x*4;                    // channels c0..c0+3
  const float As0 = -__expf(A_log[(c0+0)*DSTATE + lane]);
  const float As1 = -__expf(A_log[(c0+1)*DSTATE + lane]);
  const float As2 = -__expf(A_log[(c0+2)*DSTATE + lane]);
  const float As3 = -__expf(A_log[(c0+3)*DSTATE + lane]);
  const float4 dsk = *(const float4*)(Dskip + c0);
  const float wgt = WR[(b0 + b)*4 + DIR];
  const size_t rb = (size_t)b * NSEQ;
  const float* xd  = XDBL + rb*XW;
  const float* dtp = DT + rb*DINNER + c0;
  const float* up  = U  + rb*DINNER + c0;
  const float* zp  = XZ + rb*1536 + DINNER + c0;  // + perm(l)*1536
  float* sp = SACC + rb*DINNER + c0;

#define SLOAD(k, l) { int lr = (l) < 1023 ? (l) : 1023;                     \
    const float* x2 = xd + (size_t)lr*XW;                                   \
    B##k = x2[24+lane]; C##k = x2[88+lane];                                 \
    t##k = *(const float4*)(dtp + (size_t)lr*DINNER);                       \
    v##k = *(const float4*)(up  + (size_t)lr*DINNER);                      \
    w##k = *(const float4*)(zp  + (size_t)permi<DIR>(lr)*1536);             \
    S##k = *(const float4*)(sp  + (size_t)lr*DINNER); }

#define SSTEP(k, l) {                                                       \
    float e;                                                                \
    e = __expf(t##k.x*As0); g0 = e*g0 + (t##k.x*v##k.x)*B##k;               \
    e = __expf(t##k.y*As1); g1 = e*g1 + (t##k.y*v##k.y)*B##k;               \
    e = __expf(t##k.z*As2); g2 = e*g2 + (t##k.z*v##k.z)*B##k;               \
    e = __expf(t##k.w*As3); g3 = e*g3 + (t##k.w*v##k.w)*B##k;               \
    float p0 = wave64_reduce_hi(g0*C##k);                                   \
    float p1 = wave64_reduce_hi(g1*C##k);                                   \
    float p2 = wave64_reduce_hi(g2*C##k);                                   \
    float p3 = wave64_reduce_hi(g3*C##k);                                   \
    if (lane == 63) {                                                       \
      float4 o;                                                             \
      o.x = S##k.x + wgt*(p0 + v##k.x*dsk.x)*w##k.x;                        \
      o.y = S##k.y + wgt*(p1 + v##k.y*dsk.y)*w##k.y;                        \
      o.z = S##k.z + wgt*(p2 + v##k.z*dsk.z)*w##k.z;                        \
      o.w = S##k.w + wgt*(p3 + v##k.w*dsk.w)*w##k.w;                        \
      *(float4*)(sp + (size_t)(l)*DINNER) = o; } }

  float B0,C0,B1,C1,B2,C2,B3,C3;
  float4 t0,t1,t2,t3, v0,v1,v2,v3, w0,w1,w2,w3, S0,S1,S2,S3;
  float g0=0.f, g1=0.f, g2=0.f, g3=0.f;
  SLOAD(0,0) SLOAD(1,1) SLOAD(2,2) SLOAD(3,3)
  for (int l = 0; l < NSEQ; l += 4) {
    SSTEP(0,l)   SLOAD(0,l+4)
    SSTEP(1,l+1) SLOAD(1,l+5)
    SSTEP(2,l+2) SLOAD(2,l+6)
    SSTEP(3,l+3) SLOAD(3,l+7)
  }
#undef SLOAD
#undef SSTEP
}

// ---------------- windowed attention (W=4, heads=4, hd=96) ----------------
__global__ __launch_bounds__(256) void attn_kernel(const float* __restrict__ QKV, float* __restrict__ O){
  int idx = blockIdx.x*256 + threadIdx.x;        // (R/4 windows)*4 heads*4 q = 4R threads
  int tq = idx & 3, h = (idx >> 2) & 3, w = idx >> 4;
  size_t row0 = (size_t)w * 4;
  const float4* qp = (const float4*)(QKV + (row0 + tq)*1152 + h*96);
  float sc[4];
  #pragma unroll
  for (int tk = 0; tk < 4; ++tk) {
    const float4* kp = (const float4*)(QKV + (row0 + tk)*1152 + 384 + h*96);
    float d = 0.f;
    #pragma unroll
    for (int j = 0; j < 24; ++j) {
      float4 qf = qp[j], kf = kp[j];
      d += qf.x*kf.x + qf.y*kf.y + qf.z*kf.z + qf.w*kf.w;
    }
    sc[tk] = d * 0.10206207261596575f;           // 1/sqrt(96)
  }
  float mx = fmaxf(fmaxf(sc[0],sc[1]),fmaxf(sc[2],sc[3]));
  float s = 0.f;
  #pragma unroll
  for (int tk=0;tk<4;++tk){ sc[tk]=__expf(sc[tk]-mx); s+=sc[tk]; }
  float inv = 1.f/s;
  #pragma unroll
  for (int tk=0;tk<4;++tk) sc[tk]*=inv;
  float4* op = (float4*)(O + (row0 + tq)*DMODEL + h*96);
  #pragma unroll 4
  for (int j = 0; j < 24; ++j) {
    float4 o = {0.f,0.f,0.f,0.f};
    #pragma unroll
    for (int tk=0;tk<4;++tk){
      const float4* vp = (const float4*)(QKV + (row0+tk)*1152 + 768 + h*96);
      float4 vf = vp[j];
      o.x += sc[tk]*vf.x; o.y += sc[tk]*vf.y; o.z += sc[tk]*vf.z; o.w += sc[tk]*vf.w;
    }
    op[j] = o;
  }
}

extern "C" void kernel_launch(void* const* d_in, const int* in_sizes, int n_in,
                              void* d_out, int out_size, void* d_ws, size_t ws_size,
                              hipStream_t stream)
{
  (void)in_sizes; (void)n_in; (void)out_size;
  const float* x         = (const float*)d_in[0];
  const float* r_w1      = (const float*)d_in[1];
  const float* r_b1      = (const float*)d_in[2];
  const float* r_w2      = (const float*)d_in[3];
  const float* r_b2      = (const float*)d_in[4];
  const float* ln1_w     = (const float*)d_in[5];
  const float* ln1_b     = (const float*)d_in[6];
  const float* ln2_w     = (const float*)d_in[7];
  const float* ln2_b     = (const float*)d_in[8];
  const float* in_proj_w = (const float*)d_in[9];
  const float* conv_w    = (const float*)d_in[10];
  const float* conv_b    = (const float*)d_in[11];
  const float* x_proj_w  = (const float*)d_in[12];
  const float* dt_proj_w = (const float*)d_in[13];
  const float* dt_proj_b = (const float*)d_in[14];
  const float* A_log     = (const float*)d_in[15];
  const float* D_skip    = (const float*)d_in[16];
  const float* out_proj_w= (const float*)d_in[17];
  const float* qkv_w     = (const float*)d_in[18];
  const float* qkv_b     = (const float*)d_in[19];
  const float* ao_w      = (const float*)d_in[20];
  const float* ao_b      = (const float*)d_in[21];
  const float* gate      = (const float*)d_in[22];
  const float* lng_w     = (const float*)d_in[23];
  const float* lng_b     = (const float*)d_in[24];

  float* ws = (float*)d_ws;
  float* WR = ws;            // 32 floats
  float* G  = ws + 64;       // 3072 floats

  int BS = 8;
  while (BS > 1) {
    size_t need = ((size_t)4096 + (size_t)BS*1024*4376) * sizeof(float);
    if (need <= ws_size) break;
    BS >>= 1;
  }
  const int R = BS * 1024;   // rows per slice

  hipMemsetAsync(ws, 0, 4096*sizeof(float), stream);      // WR + G
  router_mean_kernel<<<dim3(16,8),384,0,stream>>>(x, G);
  router_mlp_kernel<<<8,96,0,stream>>>(G, r_w1, r_b1, r_w2, r_b2, WR);

  float* base = ws + 4096;
  float* XN   = base;                 // R*384
  float* XZ   = XN   + (size_t)R*384; // R*1536
  float* Ub   = XZ   + (size_t)R*1536;// R*768
  float* XDBL = Ub   + (size_t)R*768; // R*152
  float* DTb  = XDBL + (size_t)R*152; // R*768
  float* SACC = DTb  + (size_t)R*768; // R*768
  float* X2   = XN;    // out_proj output (R*384)
  float* XN2  = SACC;  // ln2 output
  float* QKV  = XZ;    // qkv output (R*1152 <= R*1536)
  float* ATTO = Ub;    // attn output
  float* AOb  = DTb;   // ao output

  for (int s = 0; s < 8/BS; ++s) {
    const int b0 = s * BS;
    const size_t xoff = (size_t)b0 * NSEQ * DMODEL;

    hipMemsetAsync(SACC, 0, (size_t)R*768*sizeof(float), stream);
    ln_kernel<<<R/4,256,0,stream>>>(x + xoff, ln1_w, ln1_b, XN);
    gemm_kernel<<<dim3(12,R/128),256,0,stream>>>(XN,384, in_proj_w,384,1536, nullptr,nullptr,0, XZ,1536);
    zsilu_kernel<<<(R*192)/256,256,0,stream>>>(XZ);   // silu(z) once, in place
    for (int dir = 0; dir < 4; ++dir) {
      switch (dir) {
        case 0: conv_silu_kernel<0><<<3*R,256,0,stream>>>(XZ, conv_w, conv_b, Ub); break;
        case 1: conv_silu_kernel<1><<<3*R,256,0,stream>>>(XZ, conv_w, conv_b, Ub); break;
        case 2: conv_silu_kernel<2><<<3*R,256,0,stream>>>(XZ, conv_w, conv_b, Ub); break;
        default: conv_silu_kernel<3><<<3*R,256,0,stream>>>(XZ, conv_w, conv_b, Ub); break;
      }
      gemm_kernel<<<dim3(2,R/128),256,0,stream>>>(Ub,768, x_proj_w,768,152, nullptr,nullptr,0, XDBL,152);
      gemm_kernel<<<dim3(6,R/128),256,0,stream>>>(XDBL,152, dt_proj_w,24,768, dt_proj_b,nullptr,1, DTb,768);
      switch (dir) {
        case 0: scan_kernel<0><<<dim3(192,BS),64,0,stream>>>(XDBL, DTb, Ub, XZ, A_log, D_skip, WR, SACC, b0); break;
        case 1: scan_kernel<1><<<dim3(192,BS),64,0,stream>>>(XDBL, DTb, Ub, XZ, A_log, D_skip, WR, SACC, b0); break;
        case 2: scan_kernel<2><<<dim3(192,BS),64,0,stream>>>(XDBL, DTb, Ub, XZ, A_log, D_skip, WR, SACC, b0); break;
        default: scan_kernel<3><<<dim3(192,BS),64,0,stream>>>(XDBL, DTb, Ub, XZ, A_log, D_skip, WR, SACC, b0); break;
      }
    }
    gemm_kernel<<<dim3(3,R/128),256,0,stream>>>(SACC,768, out_proj_w,768,384, nullptr,x + xoff,0, X2,384);
    ln_kernel<<<R/4,256,0,stream>>>(X2, ln2_w, ln2_b, XN2);
    gemm_kernel<<<dim3(9,R/128),256,0,stream>>>(XN2,384, qkv_w,384,1152, qkv_b,nullptr,0, QKV,1152);
    attn_kernel<<<R/64,256,0,stream>>>(QKV, ATTO);
    gemm_kernel<<<dim3(3,R/128),256,0,stream>>>(ATTO,384, ao_w,384,384, ao_b,nullptr,0, AOb,384);
    ln_final_kernel<<<R/4,256,0,stream>>>(XN2, AOb, gate, lng_w, lng_b, (float*)d_out + xoff);
  }
}